// Round 2
// baseline (8377.872 us; speedup 1.0000x reference)
//
#include <hip/hip_runtime.h>
#include <math.h>

namespace {

constexpr int NB    = 128;     // batch
constexpr int NPER  = 205;
constexpr int H     = 200;
constexpr int EMBD  = 768;
constexpr int SEQ   = 512;
constexpr int NLAY  = 6;
constexpr int NNODE = NB * NPER;   // 26240
constexpr int NEDGE = 209920;

__device__ __forceinline__ float sigm(float x) { return 1.0f / (1.0f + expf(-x)); }

// ---- generic tiled GEMM: C[M,N] = A[M,K] @ B (+bias) ----
// TRANSB=false: B is [K][N] row-major.  TRANSB=true: B is [N][K] row-major.
template<bool TRANSB, bool BIAS>
__global__ __launch_bounds__(256)
void gemm64(const float* __restrict__ A, const float* __restrict__ B,
            const float* __restrict__ bias, float* __restrict__ C,
            int M, int N, int K)
{
    __shared__ float As[16][68];
    __shared__ float Bs[16][68];
    const int bm = blockIdx.x * 64;
    const int bn = blockIdx.y * 64;
    const int tid = threadIdx.x;
    const int tx = tid & 15, ty = tid >> 4;
    float acc[4][4] = {};
    for (int k0 = 0; k0 < K; k0 += 16) {
        {   // A tile: As[k][m], coalesced along k
            const int k = tid & 15, m0 = tid >> 4;
            #pragma unroll
            for (int i = 0; i < 4; ++i) {
                int m = m0 + i * 16;
                int gm = bm + m, gk = k0 + k;
                As[k][m] = (gm < M && gk < K) ? A[(size_t)gm * K + gk] : 0.0f;
            }
        }
        if (!TRANSB) {
            const int n = tid & 63, kq = tid >> 6;
            #pragma unroll
            for (int i = 0; i < 4; ++i) {
                int k = kq + i * 4;
                int gk = k0 + k, gn = bn + n;
                Bs[k][n] = (gk < K && gn < N) ? B[(size_t)gk * N + gn] : 0.0f;
            }
        } else {
            const int k = tid & 15, n0 = tid >> 4;
            #pragma unroll
            for (int i = 0; i < 4; ++i) {
                int n = n0 + i * 16;
                int gn = bn + n, gk = k0 + k;
                Bs[k][n] = (gn < N && gk < K) ? B[(size_t)gn * K + gk] : 0.0f;
            }
        }
        __syncthreads();
        #pragma unroll
        for (int kk = 0; kk < 16; ++kk) {
            float a[4], b[4];
            #pragma unroll
            for (int i = 0; i < 4; ++i) a[i] = As[kk][ty * 4 + i];
            #pragma unroll
            for (int j = 0; j < 4; ++j) b[j] = Bs[kk][tx * 4 + j];
            #pragma unroll
            for (int i = 0; i < 4; ++i)
                #pragma unroll
                for (int j = 0; j < 4; ++j)
                    acc[i][j] = fmaf(a[i], b[j], acc[i][j]);
        }
        __syncthreads();
    }
    #pragma unroll
    for (int i = 0; i < 4; ++i) {
        int gm = bm + ty * 4 + i;
        if (gm >= M) continue;
        #pragma unroll
        for (int j = 0; j < 4; ++j) {
            int gn = bn + tx * 4 + j;
            if (gn >= N) continue;
            float v = acc[i][j];
            if (BIAS) v += bias[gn];
            C[(size_t)gm * N + gn] = v;
        }
    }
}

__global__ void scatter_add_kernel(const float* __restrict__ m, const int* __restrict__ src,
                                   const int* __restrict__ dst, float* __restrict__ agg)
{
    long long gid = (long long)blockIdx.x * blockDim.x + threadIdx.x;
    const long long tot = (long long)NEDGE * H;
    if (gid >= tot) return;
    int e = (int)(gid / H), c = (int)(gid % H);
    int s = src[e], d = dst[e];
    atomicAdd(&agg[(size_t)d * H + c], m[(size_t)s * H + c]);
}

__global__ void gru_update(const float* __restrict__ gi, const float* __restrict__ gh,
                           float* __restrict__ h)
{
    int gid = blockIdx.x * blockDim.x + threadIdx.x;
    if (gid >= NNODE * H) return;
    int n = gid / H, c = gid % H;
    const float* gin = gi + (size_t)n * 3 * H;
    const float* ghn = gh + (size_t)n * 3 * H;
    float r  = sigm(gin[c] + ghn[c]);
    float z  = sigm(gin[H + c] + ghn[H + c]);
    float nn = tanhf(gin[2 * H + c] + r * ghn[2 * H + c]);
    h[gid] = (1.0f - z) * nn + z * h[gid];
}

// conv0: input g[b][cin][p] = h[(b*205+p)*200+cin], K=3, pad=1, fused relu+max
__global__ __launch_bounds__(256)
void conv0_kernel(const float* __restrict__ h, const float* __restrict__ w,
                  const float* __restrict__ bias, float* __restrict__ feats)
{
    __shared__ float As[16][72];      // [cin][j], j -> p0-1+j, 66 values
    __shared__ float Ws[16][3][72];   // [cin][k][cout]
    const int p0 = blockIdx.x * 64;
    const int o0 = blockIdx.y * 64;
    const int b  = blockIdx.z;
    const int tid = threadIdx.x, tx = tid & 15, ty = tid >> 4;
    float acc[4][4] = {};
    for (int c0 = 0; c0 < H; c0 += 16) {
        {
            const int cin = tid & 15, j0 = tid >> 4;
            #pragma unroll
            for (int i = 0; i < 5; ++i) {
                int j = j0 + i * 16;
                if (j < 66) {
                    int p = p0 - 1 + j;
                    int gc = c0 + cin;
                    float v = 0.0f;
                    if (p >= 0 && p < NPER && gc < H)
                        v = h[((size_t)(b * NPER + p)) * H + gc];
                    As[cin][j] = v;
                }
            }
        }
        for (int idx = tid; idx < 64 * 48; idx += 256) {
            int o = idx / 48, ck = idx % 48;
            int cin = ck / 3, k = ck % 3;
            int go = o0 + o, gc = c0 + cin;
            float v = 0.0f;
            if (go < H && gc < H) v = w[((size_t)go * H + gc) * 3 + k];
            Ws[cin][k][o] = v;
        }
        __syncthreads();
        #pragma unroll
        for (int kk = 0; kk < 16; ++kk) {
            #pragma unroll
            for (int k = 0; k < 3; ++k) {
                float a[4], bb[4];
                #pragma unroll
                for (int i = 0; i < 4; ++i) a[i] = As[kk][ty * 4 + i + k];
                #pragma unroll
                for (int j = 0; j < 4; ++j) bb[j] = Ws[kk][k][tx * 4 + j];
                #pragma unroll
                for (int i = 0; i < 4; ++i)
                    #pragma unroll
                    for (int j = 0; j < 4; ++j)
                        acc[i][j] = fmaf(a[i], bb[j], acc[i][j]);
            }
        }
        __syncthreads();
    }
    #pragma unroll
    for (int j = 0; j < 4; ++j) {
        int o = o0 + tx * 4 + j;
        if (o >= H) continue;
        float bv = bias[o];
        float mx = 0.0f;   // relu floor
        #pragma unroll
        for (int i = 0; i < 4; ++i) {
            int p = p0 + ty * 4 + i;
            if (p < NPER) mx = fmaxf(mx, acc[i][j] + bv);
        }
        atomicMax((int*)&feats[(size_t)b * 800 + o], __float_as_int(mx));
    }
}

// conv on embeddings, gathered on the fly. K in {3,4,5}, no pad, fused relu+max.
template<int K>
__global__ __launch_bounds__(256)
void convE_kernel(const int* __restrict__ ids, const float* __restrict__ table,
                  const float* __restrict__ w, const float* __restrict__ bias,
                  float* __restrict__ feats, int feat_off)
{
    __shared__ float As[16][72];       // [cin][j], j in [0, 64+K-1)
    __shared__ float Ws[16][K][72];    // [cin][k][cout]
    __shared__ int sids[72];
    const int p0 = blockIdx.x * 64;
    const int o0 = blockIdx.y * 64;
    const int b  = blockIdx.z;
    const int tid = threadIdx.x, tx = tid & 15, ty = tid >> 4;
    const int JN = 64 + K - 1;
    if (tid < JN) {
        int p = p0 + tid;
        sids[tid] = (p < SEQ) ? ids[b * SEQ + p] : -1;
    }
    __syncthreads();
    float acc[4][4] = {};
    for (int c0 = 0; c0 < EMBD; c0 += 16) {
        {
            const int cin = tid & 15, j0 = tid >> 4;
            #pragma unroll
            for (int i = 0; i < 5; ++i) {
                int j = j0 + i * 16;
                if (j < JN) {
                    int row = sids[j];
                    As[cin][j] = (row >= 0) ? table[(size_t)row * EMBD + c0 + cin] : 0.0f;
                }
            }
        }
        for (int idx = tid; idx < 64 * 16 * K; idx += 256) {
            int o = idx / (16 * K), ck = idx % (16 * K);
            int cin = ck / K, k = ck % K;
            int go = o0 + o;
            Ws[cin][k][o] = (go < H) ? w[((size_t)go * EMBD + (c0 + cin)) * K + k] : 0.0f;
        }
        __syncthreads();
        #pragma unroll
        for (int kk = 0; kk < 16; ++kk) {
            #pragma unroll
            for (int k = 0; k < K; ++k) {
                float a[4], bb[4];
                #pragma unroll
                for (int i = 0; i < 4; ++i) a[i] = As[kk][ty * 4 + i + k];
                #pragma unroll
                for (int j = 0; j < 4; ++j) bb[j] = Ws[kk][k][tx * 4 + j];
                #pragma unroll
                for (int i = 0; i < 4; ++i)
                    #pragma unroll
                    for (int j = 0; j < 4; ++j)
                        acc[i][j] = fmaf(a[i], bb[j], acc[i][j]);
            }
        }
        __syncthreads();
    }
    const int LOUT = SEQ - K + 1;
    #pragma unroll
    for (int j = 0; j < 4; ++j) {
        int o = o0 + tx * 4 + j;
        if (o >= H) continue;
        float bv = bias[o];
        float mx = 0.0f;
        #pragma unroll
        for (int i = 0; i < 4; ++i) {
            int p = p0 + ty * 4 + i;
            if (p < LOUT) mx = fmaxf(mx, acc[i][j] + bv);
        }
        atomicMax((int*)&feats[(size_t)b * 800 + feat_off + o], __float_as_int(mx));
    }
}

__global__ __launch_bounds__(256)
void fc_head(const float* __restrict__ feats,
             const float* __restrict__ w1, const float* __restrict__ b1,
             const float* __restrict__ w2, const float* __restrict__ b2,
             const float* __restrict__ w3, const float* __restrict__ b3,
             float* __restrict__ out)
{
    __shared__ float f[800];
    __shared__ float h1[256];
    __shared__ float h2[128];
    const int b = blockIdx.x, tid = threadIdx.x;
    for (int i = tid; i < 800; i += 256) f[i] = feats[(size_t)b * 800 + i];
    __syncthreads();
    {
        float acc = b1[tid];
        const float* wr = w1 + (size_t)tid * 800;
        for (int k = 0; k < 800; ++k) acc = fmaf(f[k], wr[k], acc);
        h1[tid] = fmaxf(acc, 0.0f);
    }
    __syncthreads();
    if (tid < 128) {
        float acc = b2[tid];
        const float* wr = w2 + (size_t)tid * 256;
        for (int k = 0; k < 256; ++k) acc = fmaf(h1[k], wr[k], acc);
        h2[tid] = fmaxf(acc, 0.0f);
    }
    __syncthreads();
    if (tid < 2) {
        float acc = b3[tid];
        const float* wr = w3 + (size_t)tid * 128;
        for (int k = 0; k < 128; ++k) acc = fmaf(h2[k], wr[k], acc);
        out[(size_t)b * 2 + tid] = acc;
    }
}

} // namespace

extern "C" void kernel_launch(void* const* d_in, const int* in_sizes, int n_in,
                              void* d_out, int out_size, void* d_ws, size_t ws_size,
                              hipStream_t stream)
{
    const float* x         = (const float*)d_in[0];
    const int*   edge      = (const int*)d_in[1];
    const int*   input_ids = (const int*)d_in[2];
    const float* table     = (const float*)d_in[3];
    const float* ggc_w     = (const float*)d_in[4];
    const float* wih       = (const float*)d_in[5];
    const float* whh       = (const float*)d_in[6];
    const float* bih       = (const float*)d_in[7];
    const float* bhh       = (const float*)d_in[8];
    const float* c0w = (const float*)d_in[9];  const float* c0b = (const float*)d_in[10];
    const float* c1w = (const float*)d_in[11]; const float* c1b = (const float*)d_in[12];
    const float* c2w = (const float*)d_in[13]; const float* c2b = (const float*)d_in[14];
    const float* c3w = (const float*)d_in[15]; const float* c3b = (const float*)d_in[16];
    const float* f1w = (const float*)d_in[17]; const float* f1b = (const float*)d_in[18];
    const float* f2w = (const float*)d_in[19]; const float* f2b = (const float*)d_in[20];
    const float* f3w = (const float*)d_in[21]; const float* f3b = (const float*)d_in[22];
    float* out = (float*)d_out;

    // workspace layout (floats): h | agg | gi (m aliased at gi) | gh | feats
    float* ws   = (float*)d_ws;
    float* h    = ws;                              // 5,248,000
    float* agg  = h   + (size_t)NNODE * H;         // 5,248,000
    float* gi   = agg + (size_t)NNODE * H;         // 15,744,000 (m aliases first 1/3)
    float* gh   = gi  + (size_t)NNODE * 3 * H;     // 15,744,000
    float* feats= gh  + (size_t)NNODE * 3 * H;     // 102,400
    float* m    = gi;                               // alias: m consumed before gi written

    const int* srcp = edge;
    const int* dstp = edge + NEDGE;

    hipMemcpyAsync(h, x, sizeof(float) * (size_t)NNODE * H, hipMemcpyDeviceToDevice, stream);

    dim3 blk(256);
    for (int l = 0; l < NLAY; ++l) {
        gemm64<false, false><<<dim3(NNODE / 64, (H + 63) / 64), blk, 0, stream>>>(
            h, ggc_w + (size_t)l * H * H, nullptr, m, NNODE, H, H);
        hipMemsetAsync(agg, 0, sizeof(float) * (size_t)NNODE * H, stream);
        {
            long long tot = (long long)NEDGE * H;
            scatter_add_kernel<<<dim3((unsigned)((tot + 255) / 256)), blk, 0, stream>>>(
                m, srcp, dstp, agg);
        }
        gemm64<true, true><<<dim3(NNODE / 64, (3 * H + 63) / 64), blk, 0, stream>>>(
            agg, wih, bih, gi, NNODE, 3 * H, H);
        gemm64<true, true><<<dim3(NNODE / 64, (3 * H + 63) / 64), blk, 0, stream>>>(
            h, whh, bhh, gh, NNODE, 3 * H, H);
        gru_update<<<dim3((NNODE * H + 255) / 256), blk, 0, stream>>>(gi, gh, h);
    }

    hipMemsetAsync(feats, 0, sizeof(float) * NB * 800, stream);
    conv0_kernel<<<dim3(4, 4, NB), blk, 0, stream>>>(h, c0w, c0b, feats);
    convE_kernel<3><<<dim3(8, 4, NB), blk, 0, stream>>>(input_ids, table, c1w, c1b, feats, 200);
    convE_kernel<4><<<dim3(8, 4, NB), blk, 0, stream>>>(input_ids, table, c2w, c2b, feats, 400);
    convE_kernel<5><<<dim3(8, 4, NB), blk, 0, stream>>>(input_ids, table, c3w, c3b, feats, 600);
    fc_head<<<dim3(NB), blk, 0, stream>>>(feats, f1w, f1b, f2w, f2b, f3w, f3b, out);
}

// Round 3
// 3519.286 us; speedup vs baseline: 2.3806x; 2.3806x over previous
//
#include <hip/hip_runtime.h>
#include <math.h>

namespace {

constexpr int NB    = 128;
constexpr int NPER  = 205;
constexpr int H     = 200;
constexpr int EMBD  = 768;
constexpr int SEQ   = 512;
constexpr int NLAY  = 6;
constexpr int NNODE = NB * NPER;   // 26240
constexpr int NEDGE = 209920;

typedef __bf16 bf16;
typedef __attribute__((ext_vector_type(8))) __bf16 bf16x8;
typedef __attribute__((ext_vector_type(4))) float f32x4;
typedef unsigned short ushort8 __attribute__((ext_vector_type(8)));
typedef float float4v __attribute__((ext_vector_type(4)));

__device__ __forceinline__ float sigm(float x) { return 1.0f / (1.0f + expf(-x)); }

__device__ __forceinline__ unsigned short f2bf(float x) {
    unsigned int u = __float_as_uint(x);
    unsigned int r = (u + 0x7fffu + ((u >> 16) & 1u)) >> 16;
    return (unsigned short)r;
}

// ================= GGC (unchanged fp32 path) =================
template<bool TRANSB, bool BIAS>
__global__ __launch_bounds__(256)
void gemm64(const float* __restrict__ A, const float* __restrict__ B,
            const float* __restrict__ bias, float* __restrict__ C,
            int M, int N, int K)
{
    __shared__ float As[16][68];
    __shared__ float Bs[16][68];
    const int bm = blockIdx.x * 64;
    const int bn = blockIdx.y * 64;
    const int tid = threadIdx.x;
    const int tx = tid & 15, ty = tid >> 4;
    float acc[4][4] = {};
    for (int k0 = 0; k0 < K; k0 += 16) {
        {
            const int k = tid & 15, m0 = tid >> 4;
            #pragma unroll
            for (int i = 0; i < 4; ++i) {
                int m = m0 + i * 16;
                int gm = bm + m, gk = k0 + k;
                As[k][m] = (gm < M && gk < K) ? A[(size_t)gm * K + gk] : 0.0f;
            }
        }
        if (!TRANSB) {
            const int n = tid & 63, kq = tid >> 6;
            #pragma unroll
            for (int i = 0; i < 4; ++i) {
                int k = kq + i * 4;
                int gk = k0 + k, gn = bn + n;
                Bs[k][n] = (gk < K && gn < N) ? B[(size_t)gk * N + gn] : 0.0f;
            }
        } else {
            const int k = tid & 15, n0 = tid >> 4;
            #pragma unroll
            for (int i = 0; i < 4; ++i) {
                int n = n0 + i * 16;
                int gn = bn + n, gk = k0 + k;
                Bs[k][n] = (gn < N && gk < K) ? B[(size_t)gn * K + gk] : 0.0f;
            }
        }
        __syncthreads();
        #pragma unroll
        for (int kk = 0; kk < 16; ++kk) {
            float a[4], b[4];
            #pragma unroll
            for (int i = 0; i < 4; ++i) a[i] = As[kk][ty * 4 + i];
            #pragma unroll
            for (int j = 0; j < 4; ++j) b[j] = Bs[kk][tx * 4 + j];
            #pragma unroll
            for (int i = 0; i < 4; ++i)
                #pragma unroll
                for (int j = 0; j < 4; ++j)
                    acc[i][j] = fmaf(a[i], b[j], acc[i][j]);
        }
        __syncthreads();
    }
    #pragma unroll
    for (int i = 0; i < 4; ++i) {
        int gm = bm + ty * 4 + i;
        if (gm >= M) continue;
        #pragma unroll
        for (int j = 0; j < 4; ++j) {
            int gn = bn + tx * 4 + j;
            if (gn >= N) continue;
            float v = acc[i][j];
            if (BIAS) v += bias[gn];
            C[(size_t)gm * N + gn] = v;
        }
    }
}

__global__ void scatter_add_kernel(const float* __restrict__ m, const int* __restrict__ src,
                                   const int* __restrict__ dst, float* __restrict__ agg)
{
    long long gid = (long long)blockIdx.x * blockDim.x + threadIdx.x;
    const long long tot = (long long)NEDGE * H;
    if (gid >= tot) return;
    int e = (int)(gid / H), c = (int)(gid % H);
    int s = src[e], d = dst[e];
    atomicAdd(&agg[(size_t)d * H + c], m[(size_t)s * H + c]);
}

__global__ void gru_update(const float* __restrict__ gi, const float* __restrict__ gh,
                           float* __restrict__ h)
{
    int gid = blockIdx.x * blockDim.x + threadIdx.x;
    if (gid >= NNODE * H) return;
    int n = gid / H, c = gid % H;
    const float* gin = gi + (size_t)n * 3 * H;
    const float* ghn = gh + (size_t)n * 3 * H;
    float r  = sigm(gin[c] + ghn[c]);
    float z  = sigm(gin[H + c] + ghn[H + c]);
    float nn = tanhf(gin[2 * H + c] + r * ghn[2 * H + c]);
    h[gid] = (1.0f - z) * nn + z * h[gid];
}

// ================= bf16 conversion / packing kernels =================

// e_bf16[b*SEQ+s][EMBD] = bf16(table[ids[b][s]][:])
__global__ void embed_bf16_kernel(const int* __restrict__ ids, const float* __restrict__ table,
                                  unsigned short* __restrict__ e)
{
    int t = blockIdx.x * 256 + threadIdx.x;       // one thread per 8 elems
    const int total = NB * SEQ * (EMBD / 8);
    if (t >= total) return;
    int j = t % (EMBD / 8), row = t / (EMBD / 8);
    int id = ids[row];
    const float* src = table + (size_t)id * EMBD + j * 8;
    float4v v0 = *(const float4v*)src;
    float4v v1 = *(const float4v*)(src + 4);
    ushort8 o;
    o[0] = f2bf(v0[0]); o[1] = f2bf(v0[1]); o[2] = f2bf(v0[2]); o[3] = f2bf(v0[3]);
    o[4] = f2bf(v1[0]); o[5] = f2bf(v1[1]); o[6] = f2bf(v1[2]); o[7] = f2bf(v1[3]);
    *(ushort8*)(e + (size_t)row * EMBD + j * 8) = o;
}

// e0[b][208][256]: row 0 & rows 206,207 zero (pad), cin >= 200 zero
__global__ void h_pad_bf16_kernel(const float* __restrict__ h, unsigned short* __restrict__ e0)
{
    int t = blockIdx.x * 256 + threadIdx.x;
    const int total = NB * 208 * 32;              // per 8 elems
    if (t >= total) return;
    int c8 = t % 32, rest = t / 32;
    int r = rest % 208, b = rest / 208;
    ushort8 o = {0,0,0,0,0,0,0,0};
    if (r >= 1 && r <= 205 && c8 < 25) {
        const float* src = h + ((size_t)(b * NPER + (r - 1))) * H + c8 * 8;
        float4v v0 = *(const float4v*)src;
        float4v v1 = *(const float4v*)(src + 4);
        o[0] = f2bf(v0[0]); o[1] = f2bf(v0[1]); o[2] = f2bf(v0[2]); o[3] = f2bf(v0[3]);
        o[4] = f2bf(v1[0]); o[5] = f2bf(v1[1]); o[6] = f2bf(v1[2]); o[7] = f2bf(v1[3]);
    }
    *(ushort8*)(e0 + ((size_t)(b * 208 + r)) * 256 + c8 * 8) = o;
}

// wt[k][256][CINP] = bf16(w[o][cin][k]), zero-padded in o (>=COUT) and cin (>=CINR)
__global__ void wconv_bf16_kernel(const float* __restrict__ w, unsigned short* __restrict__ wt,
                                  int K, int CINP, int CINR, int COUT)
{
    long long t = (long long)blockIdx.x * 256 + threadIdx.x;
    long long total = (long long)K * 256 * CINP;
    if (t >= total) return;
    int cin = (int)(t % CINP);
    long long rest = t / CINP;
    int o = (int)(rest % 256), k = (int)(rest / 256);
    float v = 0.0f;
    if (o < COUT && cin < CINR) v = w[((size_t)o * CINR + cin) * K + k];
    wt[t] = f2bf(v);
}

// ================= MFMA conv + fused relu/maxpool =================
// E: [batch][LIN][CINP] bf16;  WT: [K][256][CINP] bf16
// out[p][o] = sum_{k,cin} E[p+k][cin] * WT[k][o][cin]; relu; max over p -> feats
template<int K, int CINP, int LIN, int LOUT>
__global__ __launch_bounds__(256)
void conv_mfma(const unsigned short* __restrict__ E, const unsigned short* __restrict__ WT,
               const float* __restrict__ bias, int COUT,
               float* __restrict__ feats, int foff)
{
    constexpr int BM = 128;
    constexpr int WROWS = 136;                        // >= BM+K-1, padded to 1KB staging
    constexpr int AINSTR = (WROWS * 64 * 2) / 1024;   // 17
    constexpr int BINSTR = (K * 64 * 64 * 2) / 1024;  // 8K
    __shared__ unsigned short As[WROWS * 64];         // [row][64 cin], 128B rows, swizzled
    __shared__ unsigned short Bs[K * 64 * 64];        // [k][o-row][64 cin], swizzled

    const int p0 = blockIdx.x * BM;
    const int o0 = blockIdx.y * 64;
    const int b  = blockIdx.z;
    const int tid = threadIdx.x, lane = tid & 63, wid = tid >> 6;
    const int wm = wid >> 1, wn = wid & 1;            // wave tile 64(p) x 32(o)
    const int lrow = lane & 15, lk = lane >> 4;

    const unsigned short* Eb = E + (size_t)b * LIN * CINP;

    f32x4 acc[4][2];
    #pragma unroll
    for (int i = 0; i < 4; ++i)
        #pragma unroll
        for (int j = 0; j < 2; ++j) acc[i][j] = (f32x4){0.f, 0.f, 0.f, 0.f};

    for (int c0 = 0; c0 < CINP; c0 += 64) {
        __syncthreads();
        // ---- stage A window (WROWS x 64 cin), linear LDS dest + pre-swizzled src ----
        for (int i = wid; i < AINSTR; i += 4) {
            int u = i * 64 + lane;                    // 16B unit index
            int row = u >> 3, slot = u & 7;
            int srow = p0 + row; if (srow > LIN - 1) srow = LIN - 1;
            int sslot = slot ^ (row & 7);
            const unsigned short* src = Eb + (size_t)srow * CINP + c0 + sslot * 8;
            __builtin_amdgcn_global_load_lds(
                (const __attribute__((address_space(1))) void*)src,
                (__attribute__((address_space(3))) void*)(As + i * 512), 16, 0, 0);
        }
        // ---- stage B (K taps x 64 couts x 64 cin) ----
        for (int i = wid; i < BINSTR; i += 4) {
            int u = i * 64 + lane;
            int row = u >> 3, slot = u & 7;           // row in [0, K*64)
            int k = row >> 6, r = row & 63;
            int sslot = slot ^ (r & 7);
            const unsigned short* src = WT + ((size_t)k * 256 + o0 + r) * CINP + c0 + sslot * 8;
            __builtin_amdgcn_global_load_lds(
                (const __attribute__((address_space(1))) void*)src,
                (__attribute__((address_space(3))) void*)(Bs + i * 512), 16, 0, 0);
        }
        __syncthreads();   // compiler drains vmcnt before s_barrier
        // ---- compute ----
        #pragma unroll
        for (int hf = 0; hf < 2; ++hf) {
            bf16x8 bf[K][2];
            #pragma unroll
            for (int k = 0; k < K; ++k)
                #pragma unroll
                for (int fn = 0; fn < 2; ++fn) {
                    int r = wn * 32 + fn * 16 + lrow;
                    int slot = (hf * 4 + lk) ^ (r & 7);
                    bf[k][fn] = *reinterpret_cast<const bf16x8*>(&Bs[(k * 64 + r) * 64 + slot * 8]);
                }
            #pragma unroll
            for (int k = 0; k < K; ++k) {
                bf16x8 av[4];
                #pragma unroll
                for (int fm = 0; fm < 4; ++fm) {
                    int r = wm * 64 + fm * 16 + lrow + k;
                    int slot = (hf * 4 + lk) ^ (r & 7);
                    av[fm] = *reinterpret_cast<const bf16x8*>(&As[r * 64 + slot * 8]);
                }
                #pragma unroll
                for (int fm = 0; fm < 4; ++fm)
                    #pragma unroll
                    for (int fn = 0; fn < 2; ++fn)
                        acc[fm][fn] = __builtin_amdgcn_mfma_f32_16x16x32_bf16(
                            av[fm], bf[k][fn], acc[fm][fn], 0, 0, 0);
            }
        }
    }
    // ---- epilogue: +bias, relu, max over p, one atomicMax per column ----
    #pragma unroll
    for (int fn = 0; fn < 2; ++fn) {
        int o = o0 + wn * 32 + fn * 16 + lrow;
        float mx = 0.0f;
        if (o < COUT) {
            float bv = bias[o];
            #pragma unroll
            for (int fm = 0; fm < 4; ++fm)
                #pragma unroll
                for (int i = 0; i < 4; ++i) {
                    int p = p0 + wm * 64 + fm * 16 + lk * 4 + i;
                    if (p < LOUT) mx = fmaxf(mx, acc[fm][fn][i] + bv);
                }
        }
        mx = fmaxf(mx, __shfl_xor(mx, 16));
        mx = fmaxf(mx, __shfl_xor(mx, 32));
        if (lane < 16 && o < COUT)
            atomicMax((int*)&feats[(size_t)b * 800 + foff + o], __float_as_int(mx));
    }
}

__global__ __launch_bounds__(256)
void fc_head(const float* __restrict__ feats,
             const float* __restrict__ w1, const float* __restrict__ b1,
             const float* __restrict__ w2, const float* __restrict__ b2,
             const float* __restrict__ w3, const float* __restrict__ b3,
             float* __restrict__ out)
{
    __shared__ float f[800];
    __shared__ float h1[256];
    __shared__ float h2[128];
    const int b = blockIdx.x, tid = threadIdx.x;
    for (int i = tid; i < 800; i += 256) f[i] = feats[(size_t)b * 800 + i];
    __syncthreads();
    {
        float acc = b1[tid];
        const float* wr = w1 + (size_t)tid * 800;
        for (int k = 0; k < 800; ++k) acc = fmaf(f[k], wr[k], acc);
        h1[tid] = fmaxf(acc, 0.0f);
    }
    __syncthreads();
    if (tid < 128) {
        float acc = b2[tid];
        const float* wr = w2 + (size_t)tid * 256;
        for (int k = 0; k < 256; ++k) acc = fmaf(h1[k], wr[k], acc);
        h2[tid] = fmaxf(acc, 0.0f);
    }
    __syncthreads();
    if (tid < 2) {
        float acc = b3[tid];
        const float* wr = w3 + (size_t)tid * 128;
        for (int k = 0; k < 128; ++k) acc = fmaf(h2[k], wr[k], acc);
        out[(size_t)b * 2 + tid] = acc;
    }
}

} // namespace

extern "C" void kernel_launch(void* const* d_in, const int* in_sizes, int n_in,
                              void* d_out, int out_size, void* d_ws, size_t ws_size,
                              hipStream_t stream)
{
    const float* x         = (const float*)d_in[0];
    const int*   edge      = (const int*)d_in[1];
    const int*   input_ids = (const int*)d_in[2];
    const float* table     = (const float*)d_in[3];
    const float* ggc_w     = (const float*)d_in[4];
    const float* wih       = (const float*)d_in[5];
    const float* whh       = (const float*)d_in[6];
    const float* bih       = (const float*)d_in[7];
    const float* bhh       = (const float*)d_in[8];
    const float* c0w = (const float*)d_in[9];  const float* c0b = (const float*)d_in[10];
    const float* c1w = (const float*)d_in[11]; const float* c1b = (const float*)d_in[12];
    const float* c2w = (const float*)d_in[13]; const float* c2b = (const float*)d_in[14];
    const float* c3w = (const float*)d_in[15]; const float* c3b = (const float*)d_in[16];
    const float* f1w = (const float*)d_in[17]; const float* f1b = (const float*)d_in[18];
    const float* f2w = (const float*)d_in[19]; const float* f2b = (const float*)d_in[20];
    const float* f3w = (const float*)d_in[21]; const float* f3b = (const float*)d_in[22];
    float* out = (float*)d_out;

    // ---- workspace layout (floats) ----
    float* ws    = (float*)d_ws;
    float* h     = ws;                               //  5,248,000
    float* agg   = h   + (size_t)NNODE * H;          //  5,248,000
    float* gi    = agg + (size_t)NNODE * H;          // 15,744,000
    float* gh    = gi  + (size_t)NNODE * 3 * H;      // 15,744,000
    float* feats = gh  + (size_t)NNODE * 3 * H;      //    102,400
    float* m     = gi;                               // alias (consumed before gi written)
    // conv-phase buffers alias the agg/gi/gh region (used only after GGC finishes)
    unsigned short* e_bf16 = (unsigned short*)agg;                       // 50,331,648 ush
    unsigned short* e0     = e_bf16 + (size_t)NB * SEQ * EMBD;           //  6,815,744 ush
    unsigned short* wt0    = e0 + (size_t)NB * 208 * 256;                //    196,608 ush
    unsigned short* wt1    = wt0 + (size_t)3 * 256 * 256;                //    589,824 ush
    unsigned short* wt2    = wt1 + (size_t)3 * 256 * EMBD;               //    786,432 ush
    unsigned short* wt3    = wt2 + (size_t)4 * 256 * EMBD;               //    983,040 ush

    const int* srcp = edge;
    const int* dstp = edge + NEDGE;

    hipMemcpyAsync(h, x, sizeof(float) * (size_t)NNODE * H, hipMemcpyDeviceToDevice, stream);

    dim3 blk(256);
    // ---- GGC: 6 layers (fp32) ----
    for (int l = 0; l < NLAY; ++l) {
        gemm64<false, false><<<dim3(NNODE / 64, (H + 63) / 64), blk, 0, stream>>>(
            h, ggc_w + (size_t)l * H * H, nullptr, m, NNODE, H, H);
        hipMemsetAsync(agg, 0, sizeof(float) * (size_t)NNODE * H, stream);
        {
            long long tot = (long long)NEDGE * H;
            scatter_add_kernel<<<dim3((unsigned)((tot + 255) / 256)), blk, 0, stream>>>(
                m, srcp, dstp, agg);
        }
        gemm64<true, true><<<dim3(NNODE / 64, (3 * H + 63) / 64), blk, 0, stream>>>(
            agg, wih, bih, gi, NNODE, 3 * H, H);
        gemm64<true, true><<<dim3(NNODE / 64, (3 * H + 63) / 64), blk, 0, stream>>>(
            h, whh, bhh, gh, NNODE, 3 * H, H);
        gru_update<<<dim3((NNODE * H + 255) / 256), blk, 0, stream>>>(gi, gh, h);
    }

    // ---- bf16 packing (after GGC: buffers alias agg/gi/gh) ----
    embed_bf16_kernel<<<dim3(NB * SEQ * (EMBD / 8) / 256), blk, 0, stream>>>(
        input_ids, table, e_bf16);
    h_pad_bf16_kernel<<<dim3((NB * 208 * 32 + 255) / 256), blk, 0, stream>>>(h, e0);
    wconv_bf16_kernel<<<dim3((3 * 256 * 256 + 255) / 256), blk, 0, stream>>>(c0w, wt0, 3, 256, 200, 200);
    wconv_bf16_kernel<<<dim3((3 * 256 * EMBD + 255) / 256), blk, 0, stream>>>(c1w, wt1, 3, EMBD, EMBD, 200);
    wconv_bf16_kernel<<<dim3((4 * 256 * EMBD + 255) / 256), blk, 0, stream>>>(c2w, wt2, 4, EMBD, EMBD, 200);
    wconv_bf16_kernel<<<dim3((5 * 256 * EMBD + 255) / 256), blk, 0, stream>>>(c3w, wt3, 5, EMBD, EMBD, 200);

    // ---- MFMA convs + fused relu/maxpool ----
    hipMemsetAsync(feats, 0, sizeof(float) * NB * 800, stream);
    conv_mfma<3, 256, 208, 205><<<dim3(2, 4, NB), blk, 0, stream>>>(e0, wt0, c0b, 200, feats, 0);
    conv_mfma<3, EMBD, SEQ, 510><<<dim3(4, 4, NB), blk, 0, stream>>>(e_bf16, wt1, c1b, 200, feats, 200);
    conv_mfma<4, EMBD, SEQ, 509><<<dim3(4, 4, NB), blk, 0, stream>>>(e_bf16, wt2, c2b, 200, feats, 400);
    conv_mfma<5, EMBD, SEQ, 508><<<dim3(4, 4, NB), blk, 0, stream>>>(e_bf16, wt3, c3b, 200, feats, 600);

    fc_head<<<dim3(NB), blk, 0, stream>>>(feats, f1w, f1b, f2w, f2b, f3w, f3b, out);
}

// Round 4
// 1698.999 us; speedup vs baseline: 4.9311x; 2.0714x over previous
//
#include <hip/hip_runtime.h>
#include <math.h>

namespace {

constexpr int NB    = 128;
constexpr int NPER  = 205;
constexpr int H     = 200;
constexpr int EMBD  = 768;
constexpr int SEQ   = 512;
constexpr int NLAY  = 6;
constexpr int NNODE = NB * NPER;   // 26240
constexpr int NEDGE = 209920;

typedef __bf16 bf16;
typedef __attribute__((ext_vector_type(8))) __bf16 bf16x8;
typedef __attribute__((ext_vector_type(4))) float f32x4;
typedef unsigned short ushort8 __attribute__((ext_vector_type(8)));
typedef float float4v __attribute__((ext_vector_type(4)));

__device__ __forceinline__ float sigm(float x) { return 1.0f / (1.0f + expf(-x)); }

__device__ __forceinline__ unsigned short f2bf(float x) {
    unsigned int u = __float_as_uint(x);
    unsigned int r = (u + 0x7fffu + ((u >> 16) & 1u)) >> 16;
    return (unsigned short)r;
}
__device__ __forceinline__ float bf2f(unsigned short u) {
    return __uint_as_float(((unsigned int)u) << 16);
}
__device__ __forceinline__ void fsplit(float x, unsigned short& hi, unsigned short& lo) {
    hi = f2bf(x);
    lo = f2bf(x - bf2f(hi));
}

// ================= split-bf16 MFMA GEMM =================
// C[M][Nreal] (+bias) = A[M][K] @ B^T ; A given as hi/lo bf16 [M][lda] (cols c in [0,Kpad))
// B given as hi/lo bf16 [Npad][Kpad], row-major K-contiguous (row = output col).
// 3-term split product: hi*hi + hi*lo + lo*hi  (~2^-17 rel error).
template<bool BIAS, bool OUTSPLIT>
__global__ __launch_bounds__(256)
void gemm_split_mfma(const unsigned short* __restrict__ Ahi, const unsigned short* __restrict__ Alo,
                     int lda,
                     const unsigned short* __restrict__ Bhi, const unsigned short* __restrict__ Blo,
                     const float* __restrict__ bias, int Nreal,
                     float* __restrict__ Cf,
                     unsigned short* __restrict__ Chi, unsigned short* __restrict__ Clo,
                     int ldc, int Kpad)
{
    __shared__ unsigned short Ah[128 * 64];
    __shared__ unsigned short Al[128 * 64];
    __shared__ unsigned short Bh[64 * 64];
    __shared__ unsigned short Bl[64 * 64];

    const int p0 = blockIdx.x * 128;
    const int o0 = blockIdx.y * 64;
    const int tid = threadIdx.x, lane = tid & 63, wid = tid >> 6;
    const int wm = wid >> 1, wn = wid & 1;
    const int lrow = lane & 15, lk = lane >> 4;

    f32x4 acc[4][2];
    #pragma unroll
    for (int i = 0; i < 4; ++i)
        #pragma unroll
        for (int j = 0; j < 2; ++j) acc[i][j] = (f32x4){0.f, 0.f, 0.f, 0.f};

    for (int c0 = 0; c0 < Kpad; c0 += 64) {
        __syncthreads();
        for (int i = wid; i < 16; i += 4) {
            int u = i * 64 + lane;
            int row = u >> 3, slot = u & 7;
            int ss = slot ^ (row & 7);
            const unsigned short* sA = Ahi + (size_t)(p0 + row) * lda + c0 + ss * 8;
            __builtin_amdgcn_global_load_lds(
                (const __attribute__((address_space(1))) void*)sA,
                (__attribute__((address_space(3))) void*)(Ah + i * 512), 16, 0, 0);
            const unsigned short* sA2 = Alo + (size_t)(p0 + row) * lda + c0 + ss * 8;
            __builtin_amdgcn_global_load_lds(
                (const __attribute__((address_space(1))) void*)sA2,
                (__attribute__((address_space(3))) void*)(Al + i * 512), 16, 0, 0);
        }
        for (int i = wid; i < 8; i += 4) {
            int u = i * 64 + lane;
            int row = u >> 3, slot = u & 7;
            int ss = slot ^ (row & 7);
            const unsigned short* sB = Bhi + (size_t)(o0 + row) * Kpad + c0 + ss * 8;
            __builtin_amdgcn_global_load_lds(
                (const __attribute__((address_space(1))) void*)sB,
                (__attribute__((address_space(3))) void*)(Bh + i * 512), 16, 0, 0);
            const unsigned short* sB2 = Blo + (size_t)(o0 + row) * Kpad + c0 + ss * 8;
            __builtin_amdgcn_global_load_lds(
                (const __attribute__((address_space(1))) void*)sB2,
                (__attribute__((address_space(3))) void*)(Bl + i * 512), 16, 0, 0);
        }
        __syncthreads();
        #pragma unroll
        for (int hf = 0; hf < 2; ++hf) {
            bf16x8 vbh[2], vbl[2];
            #pragma unroll
            for (int fn = 0; fn < 2; ++fn) {
                int r = wn * 32 + fn * 16 + lrow;
                int sl = (hf * 4 + lk) ^ (r & 7);
                vbh[fn] = *reinterpret_cast<const bf16x8*>(&Bh[r * 64 + sl * 8]);
                vbl[fn] = *reinterpret_cast<const bf16x8*>(&Bl[r * 64 + sl * 8]);
            }
            #pragma unroll
            for (int fm = 0; fm < 4; ++fm) {
                int r = wm * 64 + fm * 16 + lrow;
                int sl = (hf * 4 + lk) ^ (r & 7);
                bf16x8 vah = *reinterpret_cast<const bf16x8*>(&Ah[r * 64 + sl * 8]);
                bf16x8 val = *reinterpret_cast<const bf16x8*>(&Al[r * 64 + sl * 8]);
                #pragma unroll
                for (int fn = 0; fn < 2; ++fn) {
                    acc[fm][fn] = __builtin_amdgcn_mfma_f32_16x16x32_bf16(vah, vbh[fn], acc[fm][fn], 0, 0, 0);
                    acc[fm][fn] = __builtin_amdgcn_mfma_f32_16x16x32_bf16(vah, vbl[fn], acc[fm][fn], 0, 0, 0);
                    acc[fm][fn] = __builtin_amdgcn_mfma_f32_16x16x32_bf16(val, vbh[fn], acc[fm][fn], 0, 0, 0);
                }
            }
        }
    }
    #pragma unroll
    for (int fn = 0; fn < 2; ++fn) {
        int o = o0 + wn * 32 + fn * 16 + lrow;
        if (o >= Nreal) continue;
        float bv = BIAS ? bias[o] : 0.0f;
        #pragma unroll
        for (int fm = 0; fm < 4; ++fm) {
            #pragma unroll
            for (int i = 0; i < 4; ++i) {
                int p = p0 + wm * 64 + fm * 16 + lk * 4 + i;
                float v = acc[fm][fn][i] + bv;
                if (OUTSPLIT) {
                    unsigned short hi, lo;
                    fsplit(v, hi, lo);
                    Chi[(size_t)p * ldc + o] = hi;
                    Clo[(size_t)p * ldc + o] = lo;
                } else {
                    Cf[(size_t)p * ldc + o] = v;
                }
            }
        }
    }
}

// ================= CSR build =================
__global__ void hist_kernel(const int* __restrict__ dst, int* __restrict__ deg)
{
    int e = blockIdx.x * 256 + threadIdx.x;
    if (e < NEDGE) atomicAdd(&deg[dst[e]], 1);
}

__global__ void scan_kernel(const int* __restrict__ deg, int* __restrict__ off, int* __restrict__ cur)
{
    __shared__ int part[1024];
    const int tid = threadIdx.x;
    const int CH = (NNODE + 1023) / 1024;
    int base = tid * CH;
    int s = 0;
    for (int i = 0; i < CH; ++i) { int idx = base + i; s += (idx < NNODE ? deg[idx] : 0); }
    part[tid] = s;
    __syncthreads();
    for (int d = 1; d < 1024; d <<= 1) {
        int v = (tid >= d) ? part[tid - d] : 0;
        __syncthreads();
        part[tid] += v;
        __syncthreads();
    }
    int run = tid ? part[tid - 1] : 0;
    for (int i = 0; i < CH; ++i) {
        int idx = base + i;
        if (idx < NNODE) { off[idx] = run; cur[idx] = run; run += deg[idx]; }
    }
    if (tid == 1023) off[NNODE] = run;
}

__global__ void fill_kernel(const int* __restrict__ src, const int* __restrict__ dst,
                            int* __restrict__ cur, int* __restrict__ eidx)
{
    int e = blockIdx.x * 256 + threadIdx.x;
    if (e >= NEDGE) return;
    int d = dst[e];
    int pos = atomicAdd(&cur[d], 1);
    eidx[pos] = src[e];
}

// ================= per-layer kernels =================
// gather: agg[n] = sum over in-edges of m[src]; write split into acat cols [0,256)
__global__ void gather_split(const unsigned short* __restrict__ m_hi,
                             const unsigned short* __restrict__ m_lo,
                             const int* __restrict__ off, const int* __restrict__ eidx,
                             unsigned short* __restrict__ acat_hi, unsigned short* __restrict__ acat_lo)
{
    int t = blockIdx.x * 256 + threadIdx.x;
    if (t >= NNODE * 32) return;
    int c8 = t & 31, n = t >> 5;
    float s[8] = {0.f, 0.f, 0.f, 0.f, 0.f, 0.f, 0.f, 0.f};
    if (c8 < 25) {
        const size_t cb = (size_t)c8 * 8;
        int beg = off[n], end = off[n + 1];
        for (int i = beg; i < end; ++i) {
            int sn = eidx[i];
            ushort8 mh = *(const ushort8*)(m_hi + (size_t)sn * 208 + cb);
            ushort8 ml = *(const ushort8*)(m_lo + (size_t)sn * 208 + cb);
            #pragma unroll
            for (int j = 0; j < 8; ++j) s[j] += bf2f(mh[j]) + bf2f(ml[j]);
        }
    }
    ushort8 oh, ol;
    #pragma unroll
    for (int j = 0; j < 8; ++j) { unsigned short hi, lo; fsplit(s[j], hi, lo); oh[j] = hi; ol[j] = lo; }
    *(ushort8*)(acat_hi + (size_t)n * 512 + c8 * 8) = oh;
    *(ushort8*)(acat_lo + (size_t)n * 512 + c8 * 8) = ol;
}

// GRU update: h_new from S_rz (r,z pre-acts), inn, hn; h stored split in acat cols [256,512)
__global__ void gru_kernel(const float* __restrict__ Srz, const float* __restrict__ inn,
                           const float* __restrict__ hn,
                           unsigned short* __restrict__ acat_hi, unsigned short* __restrict__ acat_lo)
{
    int gid = blockIdx.x * 256 + threadIdx.x;
    if (gid >= NNODE * H) return;
    int n = gid / H, c = gid % H;
    float r = sigm(Srz[(size_t)n * 400 + c]);
    float z = sigm(Srz[(size_t)n * 400 + 200 + c]);
    float nn = tanhf(inn[(size_t)n * 200 + c] + r * hn[(size_t)n * 200 + c]);
    size_t hidx = (size_t)n * 512 + 256 + c;
    float h_old = bf2f(acat_hi[hidx]) + bf2f(acat_lo[hidx]);
    float hnew = (1.0f - z) * nn + z * h_old;
    unsigned short hi, lo;
    fsplit(hnew, hi, lo);
    acat_hi[hidx] = hi;
    acat_lo[hidx] = lo;
}

// initial h = x, split into acat cols [256,512); zero the pad cols
__global__ void h0_split(const float* __restrict__ x,
                         unsigned short* __restrict__ acat_hi, unsigned short* __restrict__ acat_lo)
{
    int t = blockIdx.x * 256 + threadIdx.x;
    if (t >= NNODE * 32) return;
    int c8 = t & 31, n = t >> 5;
    ushort8 oh = {0,0,0,0,0,0,0,0}, ol = {0,0,0,0,0,0,0,0};
    if (c8 < 25) {
        const float* src = x + (size_t)n * H + c8 * 8;
        float4v v0 = *(const float4v*)src;
        float4v v1 = *(const float4v*)(src + 4);
        float v[8] = {v0[0], v0[1], v0[2], v0[3], v1[0], v1[1], v1[2], v1[3]};
        #pragma unroll
        for (int j = 0; j < 8; ++j) { unsigned short hi, lo; fsplit(v[j], hi, lo); oh[j] = hi; ol[j] = lo; }
    }
    *(ushort8*)(acat_hi + (size_t)n * 512 + 256 + c8 * 8) = oh;
    *(ushort8*)(acat_lo + (size_t)n * 512 + 256 + c8 * 8) = ol;
}

// ================= weight prep =================
// ggc_w[l][in][out] -> wg[l][out(256)][in(256)] split
__global__ void ggcw_split(const float* __restrict__ w,
                           unsigned short* __restrict__ whi, unsigned short* __restrict__ wlo)
{
    int t = blockIdx.x * 256 + threadIdx.x;
    if (t >= NLAY * 256 * 32) return;
    int c8 = t & 31;
    int rest = t >> 5;
    int n = rest & 255;
    int l = rest >> 8;
    ushort8 oh = {0,0,0,0,0,0,0,0}, ol = {0,0,0,0,0,0,0,0};
    #pragma unroll
    for (int j = 0; j < 8; ++j) {
        int k = c8 * 8 + j;
        float v = 0.0f;
        if (n < H && k < H) v = w[(size_t)l * H * H + (size_t)k * H + n];
        unsigned short hi, lo; fsplit(v, hi, lo); oh[j] = hi; ol[j] = lo;
    }
    *(ushort8*)(whi + (size_t)l * 65536 + (size_t)n * 256 + c8 * 8) = oh;
    *(ushort8*)(wlo + (size_t)l * 65536 + (size_t)n * 256 + c8 * 8) = ol;
}

// wcat[448][512]: row r<400: cols 0..199 = wih[r], cols 256..455 = whh[r]
__global__ void wcat_split(const float* __restrict__ wih, const float* __restrict__ whh,
                           unsigned short* __restrict__ whi, unsigned short* __restrict__ wlo)
{
    int t = blockIdx.x * 256 + threadIdx.x;
    if (t >= 448 * 64) return;
    int k8 = t & 63, r = t >> 6;
    ushort8 oh = {0,0,0,0,0,0,0,0}, ol = {0,0,0,0,0,0,0,0};
    #pragma unroll
    for (int j = 0; j < 8; ++j) {
        int kk = k8 * 8 + j;
        float v = 0.0f;
        if (r < 400) {
            if (kk < H) v = wih[(size_t)r * H + kk];
            else if (kk >= 256 && kk < 256 + H) v = whh[(size_t)r * H + (kk - 256)];
        }
        unsigned short hi, lo; fsplit(v, hi, lo); oh[j] = hi; ol[j] = lo;
    }
    *(ushort8*)(whi + (size_t)r * 512 + k8 * 8) = oh;
    *(ushort8*)(wlo + (size_t)r * 512 + k8 * 8) = ol;
}

// generic: src row-major [*, ncr], rows srow0.., -> [Npad=256][Kpad=256] split
__global__ void wsplit_kernel(const float* __restrict__ src, int srow0,
                              unsigned short* __restrict__ whi, unsigned short* __restrict__ wlo)
{
    int t = blockIdx.x * 256 + threadIdx.x;
    if (t >= 256 * 32) return;
    int k8 = t & 31, r = t >> 5;
    ushort8 oh = {0,0,0,0,0,0,0,0}, ol = {0,0,0,0,0,0,0,0};
    #pragma unroll
    for (int j = 0; j < 8; ++j) {
        int k = k8 * 8 + j;
        float v = 0.0f;
        if (r < H && k < H) v = src[(size_t)(srow0 + r) * H + k];
        unsigned short hi, lo; fsplit(v, hi, lo); oh[j] = hi; ol[j] = lo;
    }
    *(ushort8*)(whi + (size_t)r * 256 + k8 * 8) = oh;
    *(ushort8*)(wlo + (size_t)r * 256 + k8 * 8) = ol;
}

__global__ void bias_prep(const float* __restrict__ bih, const float* __restrict__ bhh,
                          float* __restrict__ b_rz, float* __restrict__ b_inn, float* __restrict__ b_hn)
{
    int t = threadIdx.x;
    if (t < 400) b_rz[t] = bih[t] + bhh[t];
    if (t < 200) { b_inn[t] = bih[400 + t]; b_hn[t] = bhh[400 + t]; }
}

// ================= conv phase (round-3, verified) =================
__global__ void embed_bf16_kernel(const int* __restrict__ ids, const float* __restrict__ table,
                                  unsigned short* __restrict__ e)
{
    int t = blockIdx.x * 256 + threadIdx.x;
    const int total = NB * SEQ * (EMBD / 8);
    if (t >= total) return;
    int j = t % (EMBD / 8), row = t / (EMBD / 8);
    int id = ids[row];
    const float* src = table + (size_t)id * EMBD + j * 8;
    float4v v0 = *(const float4v*)src;
    float4v v1 = *(const float4v*)(src + 4);
    ushort8 o;
    o[0] = f2bf(v0[0]); o[1] = f2bf(v0[1]); o[2] = f2bf(v0[2]); o[3] = f2bf(v0[3]);
    o[4] = f2bf(v1[0]); o[5] = f2bf(v1[1]); o[6] = f2bf(v1[2]); o[7] = f2bf(v1[3]);
    *(ushort8*)(e + (size_t)row * EMBD + j * 8) = o;
}

// e0[b][208][256] from acat_hi h-part (bf16 h), rows 1..205 = nodes, pad rows zero
__global__ void h_pad_from_acat(const unsigned short* __restrict__ acat_hi,
                                unsigned short* __restrict__ e0)
{
    int t = blockIdx.x * 256 + threadIdx.x;
    const int total = NB * 208 * 32;
    if (t >= total) return;
    int c8 = t % 32, rest = t / 32;
    int r = rest % 208, b = rest / 208;
    ushort8 o = {0,0,0,0,0,0,0,0};
    if (r >= 1 && r <= 205) {
        int node = b * NPER + (r - 1);
        o = *(const ushort8*)(acat_hi + (size_t)node * 512 + 256 + c8 * 8);
    }
    *(ushort8*)(e0 + ((size_t)(b * 208 + r)) * 256 + c8 * 8) = o;
}

__global__ void wconv_bf16_kernel(const float* __restrict__ w, unsigned short* __restrict__ wt,
                                  int K, int CINP, int CINR, int COUT)
{
    long long t = (long long)blockIdx.x * 256 + threadIdx.x;
    long long total = (long long)K * 256 * CINP;
    if (t >= total) return;
    int cin = (int)(t % CINP);
    long long rest = t / CINP;
    int o = (int)(rest % 256), k = (int)(rest / 256);
    float v = 0.0f;
    if (o < COUT && cin < CINR) v = w[((size_t)o * CINR + cin) * K + k];
    wt[t] = f2bf(v);
}

template<int K, int CINP, int LIN, int LOUT>
__global__ __launch_bounds__(256)
void conv_mfma(const unsigned short* __restrict__ E, const unsigned short* __restrict__ WT,
               const float* __restrict__ bias, int COUT,
               float* __restrict__ feats, int foff)
{
    constexpr int BM = 128;
    constexpr int WROWS = 136;
    constexpr int AINSTR = (WROWS * 64 * 2) / 1024;
    constexpr int BINSTR = (K * 64 * 64 * 2) / 1024;
    __shared__ unsigned short As[WROWS * 64];
    __shared__ unsigned short Bs[K * 64 * 64];

    const int p0 = blockIdx.x * BM;
    const int o0 = blockIdx.y * 64;
    const int b  = blockIdx.z;
    const int tid = threadIdx.x, lane = tid & 63, wid = tid >> 6;
    const int wm = wid >> 1, wn = wid & 1;
    const int lrow = lane & 15, lk = lane >> 4;

    const unsigned short* Eb = E + (size_t)b * LIN * CINP;

    f32x4 acc[4][2];
    #pragma unroll
    for (int i = 0; i < 4; ++i)
        #pragma unroll
        for (int j = 0; j < 2; ++j) acc[i][j] = (f32x4){0.f, 0.f, 0.f, 0.f};

    for (int c0 = 0; c0 < CINP; c0 += 64) {
        __syncthreads();
        for (int i = wid; i < AINSTR; i += 4) {
            int u = i * 64 + lane;
            int row = u >> 3, slot = u & 7;
            int srow = p0 + row; if (srow > LIN - 1) srow = LIN - 1;
            int sslot = slot ^ (row & 7);
            const unsigned short* src = Eb + (size_t)srow * CINP + c0 + sslot * 8;
            __builtin_amdgcn_global_load_lds(
                (const __attribute__((address_space(1))) void*)src,
                (__attribute__((address_space(3))) void*)(As + i * 512), 16, 0, 0);
        }
        for (int i = wid; i < BINSTR; i += 4) {
            int u = i * 64 + lane;
            int row = u >> 3, slot = u & 7;
            int k = row >> 6, r = row & 63;
            int sslot = slot ^ (r & 7);
            const unsigned short* src = WT + ((size_t)k * 256 + o0 + r) * CINP + c0 + sslot * 8;
            __builtin_amdgcn_global_load_lds(
                (const __attribute__((address_space(1))) void*)src,
                (__attribute__((address_space(3))) void*)(Bs + i * 512), 16, 0, 0);
        }
        __syncthreads();
        #pragma unroll
        for (int hf = 0; hf < 2; ++hf) {
            bf16x8 bf[K][2];
            #pragma unroll
            for (int k = 0; k < K; ++k)
                #pragma unroll
                for (int fn = 0; fn < 2; ++fn) {
                    int r = wn * 32 + fn * 16 + lrow;
                    int slot = (hf * 4 + lk) ^ (r & 7);
                    bf[k][fn] = *reinterpret_cast<const bf16x8*>(&Bs[(k * 64 + r) * 64 + slot * 8]);
                }
            #pragma unroll
            for (int k = 0; k < K; ++k) {
                bf16x8 av[4];
                #pragma unroll
                for (int fm = 0; fm < 4; ++fm) {
                    int r = wm * 64 + fm * 16 + lrow + k;
                    int slot = (hf * 4 + lk) ^ (r & 7);
                    av[fm] = *reinterpret_cast<const bf16x8*>(&As[r * 64 + slot * 8]);
                }
                #pragma unroll
                for (int fm = 0; fm < 4; ++fm)
                    #pragma unroll
                    for (int fn = 0; fn < 2; ++fn)
                        acc[fm][fn] = __builtin_amdgcn_mfma_f32_16x16x32_bf16(
                            av[fm], bf[k][fn], acc[fm][fn], 0, 0, 0);
            }
        }
    }
    #pragma unroll
    for (int fn = 0; fn < 2; ++fn) {
        int o = o0 + wn * 32 + fn * 16 + lrow;
        float mx = 0.0f;
        if (o < COUT) {
            float bv = bias[o];
            #pragma unroll
            for (int fm = 0; fm < 4; ++fm)
                #pragma unroll
                for (int i = 0; i < 4; ++i) {
                    int p = p0 + wm * 64 + fm * 16 + lk * 4 + i;
                    if (p < LOUT) mx = fmaxf(mx, acc[fm][fn][i] + bv);
                }
        }
        mx = fmaxf(mx, __shfl_xor(mx, 16));
        mx = fmaxf(mx, __shfl_xor(mx, 32));
        if (lane < 16 && o < COUT)
            atomicMax((int*)&feats[(size_t)b * 800 + foff + o], __float_as_int(mx));
    }
}

__global__ __launch_bounds__(256)
void fc_head(const float* __restrict__ feats,
             const float* __restrict__ w1, const float* __restrict__ b1,
             const float* __restrict__ w2, const float* __restrict__ b2,
             const float* __restrict__ w3, const float* __restrict__ b3,
             float* __restrict__ out)
{
    __shared__ float f[800];
    __shared__ float h1[256];
    __shared__ float h2[128];
    const int b = blockIdx.x, tid = threadIdx.x;
    for (int i = tid; i < 800; i += 256) f[i] = feats[(size_t)b * 800 + i];
    __syncthreads();
    {
        float acc = b1[tid];
        const float* wr = w1 + (size_t)tid * 800;
        for (int k = 0; k < 800; ++k) acc = fmaf(f[k], wr[k], acc);
        h1[tid] = fmaxf(acc, 0.0f);
    }
    __syncthreads();
    if (tid < 128) {
        float acc = b2[tid];
        const float* wr = w2 + (size_t)tid * 256;
        for (int k = 0; k < 256; ++k) acc = fmaf(h1[k], wr[k], acc);
        h2[tid] = fmaxf(acc, 0.0f);
    }
    __syncthreads();
    if (tid < 2) {
        float acc = b3[tid];
        const float* wr = w3 + (size_t)tid * 128;
        for (int k = 0; k < 128; ++k) acc = fmaf(h2[k], wr[k], acc);
        out[(size_t)b * 2 + tid] = acc;
    }
}

} // namespace

extern "C" void kernel_launch(void* const* d_in, const int* in_sizes, int n_in,
                              void* d_out, int out_size, void* d_ws, size_t ws_size,
                              hipStream_t stream)
{
    const float* x         = (const float*)d_in[0];
    const int*   edge      = (const int*)d_in[1];
    const int*   input_ids = (const int*)d_in[2];
    const float* table     = (const float*)d_in[3];
    const float* ggc_w     = (const float*)d_in[4];
    const float* wih       = (const float*)d_in[5];
    const float* whh       = (const float*)d_in[6];
    const float* bih       = (const float*)d_in[7];
    const float* bhh       = (const float*)d_in[8];
    const float* c0w = (const float*)d_in[9];  const float* c0b = (const float*)d_in[10];
    const float* c1w = (const float*)d_in[11]; const float* c1b = (const float*)d_in[12];
    const float* c2w = (const float*)d_in[13]; const float* c2b = (const float*)d_in[14];
    const float* c3w = (const float*)d_in[15]; const float* c3b = (const float*)d_in[16];
    const float* f1w = (const float*)d_in[17]; const float* f1b = (const float*)d_in[18];
    const float* f2w = (const float*)d_in[19]; const float* f2b = (const float*)d_in[20];
    const float* f3w = (const float*)d_in[21]; const float* f3b = (const float*)d_in[22];
    float* out = (float*)d_out;

    // ---- workspace layout (float-slot offsets) ----
    float* ws = (float*)d_ws;
    unsigned short* acat_hi = (unsigned short*)(ws + 0);            // 26240*512 ush
    unsigned short* acat_lo = (unsigned short*)(ws + 6717440);
    float* Srz   = ws + 13434880;                                   // 26240*400
    float* inn   = ws + 23930880;                                   // 26240*200
    float* hn    = ws + 29178880;                                   // 26240*200
    unsigned short* m_hi = (unsigned short*)(ws + 34426880);        // 26240*208 ush
    unsigned short* m_lo = (unsigned short*)(ws + 37155840);
    unsigned short* wg_hi  = (unsigned short*)(ws + 39884800);      // 6*256*256
    unsigned short* wg_lo  = (unsigned short*)(ws + 40081408);
    unsigned short* wc_hi  = (unsigned short*)(ws + 40278016);      // 448*512
    unsigned short* wc_lo  = (unsigned short*)(ws + 40392704);
    unsigned short* win_hi = (unsigned short*)(ws + 40507392);      // 256*256
    unsigned short* win_lo = (unsigned short*)(ws + 40540160);
    unsigned short* whn_hi = (unsigned short*)(ws + 40572928);
    unsigned short* whn_lo = (unsigned short*)(ws + 40605696);
    float* b_rz  = ws + 40638464;                                   // 400
    float* b_inn = ws + 40638864;                                   // 200
    float* b_hn  = ws + 40639064;                                   // 200
    int* deg  = (int*)(ws + 40639264);                              // 26240
    int* off  = (int*)(ws + 40665504);                              // 26241
    int* cur  = (int*)(ws + 40691745);                              // 26241
    int* eidx = (int*)(ws + 40717986);                              // 209920
    float* feats = ws + 40927906;                                   // 128*800
    // conv-phase aliases (all GGC buffers dead by then):
    unsigned short* e_bf16 = (unsigned short*)(ws + 0);             // 128*512*768 ush = 25,165,824 f
    unsigned short* e0     = (unsigned short*)(ws + 25165824);      // 128*208*256 ush = 6,815,744 f
    unsigned short* wt0    = (unsigned short*)(ws + 34426880);      // 2,555,904 ush total
    unsigned short* wt1    = wt0 + (size_t)3 * 256 * 256;
    unsigned short* wt2    = wt1 + (size_t)3 * 256 * EMBD;
    unsigned short* wt3    = wt2 + (size_t)4 * 256 * EMBD;

    const int* srcp = edge;
    const int* dstp = edge + NEDGE;

    dim3 blk(256);

    // ---- one-time prep ----
    bias_prep<<<dim3(1), dim3(512), 0, stream>>>(bih, bhh, b_rz, b_inn, b_hn);
    hipMemsetAsync(deg, 0, sizeof(int) * NNODE, stream);
    hist_kernel<<<dim3((NEDGE + 255) / 256), blk, 0, stream>>>(dstp, deg);
    scan_kernel<<<dim3(1), dim3(1024), 0, stream>>>(deg, off, cur);
    fill_kernel<<<dim3((NEDGE + 255) / 256), blk, 0, stream>>>(srcp, dstp, cur, eidx);
    h0_split<<<dim3((NNODE * 32 + 255) / 256), blk, 0, stream>>>(x, acat_hi, acat_lo);
    ggcw_split<<<dim3((NLAY * 256 * 32 + 255) / 256), blk, 0, stream>>>(ggc_w, wg_hi, wg_lo);
    wcat_split<<<dim3((448 * 64 + 255) / 256), blk, 0, stream>>>(wih, whh, wc_hi, wc_lo);
    wsplit_kernel<<<dim3((256 * 32 + 255) / 256), blk, 0, stream>>>(wih, 400, win_hi, win_lo);
    wsplit_kernel<<<dim3((256 * 32 + 255) / 256), blk, 0, stream>>>(whh, 400, whn_hi, whn_lo);

    // ---- GGC layers ----
    const int GX = NNODE / 128;   // 205
    for (int l = 0; l < NLAY; ++l) {
        // m = h @ W_l  (split out)
        gemm_split_mfma<false, true><<<dim3(GX, 4), blk, 0, stream>>>(
            acat_hi + 256, acat_lo + 256, 512,
            wg_hi + (size_t)l * 65536, wg_lo + (size_t)l * 65536,
            nullptr, 200, nullptr, m_hi, m_lo, 208, 256);
        // agg = gather(m)
        gather_split<<<dim3((NNODE * 32 + 255) / 256), blk, 0, stream>>>(
            m_hi, m_lo, off, eidx, acat_hi, acat_lo);
        // S_rz = [agg|h] @ wcat^T + (bih+bhh)[0:400]
        gemm_split_mfma<true, false><<<dim3(GX, 7), blk, 0, stream>>>(
            acat_hi, acat_lo, 512, wc_hi, wc_lo,
            b_rz, 400, Srz, nullptr, nullptr, 400, 512);
        // inn = agg @ wih_n^T + bih_n
        gemm_split_mfma<true, false><<<dim3(GX, 4), blk, 0, stream>>>(
            acat_hi, acat_lo, 512, win_hi, win_lo,
            b_inn, 200, inn, nullptr, nullptr, 200, 256);
        // hn = h @ whh_n^T + bhh_n
        gemm_split_mfma<true, false><<<dim3(GX, 4), blk, 0, stream>>>(
            acat_hi + 256, acat_lo + 256, 512, whn_hi, whn_lo,
            b_hn, 200, hn, nullptr, nullptr, 200, 256);
        // GRU update (h part of acat)
        gru_kernel<<<dim3((NNODE * H + 255) / 256), blk, 0, stream>>>(
            Srz, inn, hn, acat_hi, acat_lo);
    }

    // ---- conv phase ----
    // e0 first (reads acat), then e_bf16 may overwrite acat
    h_pad_from_acat<<<dim3((NB * 208 * 32 + 255) / 256), blk, 0, stream>>>(acat_hi, e0);
    embed_bf16_kernel<<<dim3(NB * SEQ * (EMBD / 8) / 256), blk, 0, stream>>>(input_ids, table, e_bf16);
    wconv_bf16_kernel<<<dim3((3 * 256 * 256 + 255) / 256), blk, 0, stream>>>(c0w, wt0, 3, 256, 200, 200);
    wconv_bf16_kernel<<<dim3((3 * 256 * EMBD + 255) / 256), blk, 0, stream>>>(c1w, wt1, 3, EMBD, EMBD, 200);
    wconv_bf16_kernel<<<dim3((4 * 256 * EMBD + 255) / 256), blk, 0, stream>>>(c2w, wt2, 4, EMBD, EMBD, 200);
    wconv_bf16_kernel<<<dim3((5 * 256 * EMBD + 255) / 256), blk, 0, stream>>>(c3w, wt3, 5, EMBD, EMBD, 200);

    hipMemsetAsync(feats, 0, sizeof(float) * NB * 800, stream);
    conv_mfma<3, 256, 208, 205><<<dim3(2, 4, NB), blk, 0, stream>>>(e0, wt0, c0b, 200, feats, 0);
    conv_mfma<3, EMBD, SEQ, 510><<<dim3(4, 4, NB), blk, 0, stream>>>(e_bf16, wt1, c1b, 200, feats, 200);
    conv_mfma<4, EMBD, SEQ, 509><<<dim3(4, 4, NB), blk, 0, stream>>>(e_bf16, wt2, c2b, 200, feats, 400);
    conv_mfma<5, EMBD, SEQ, 508><<<dim3(4, 4, NB), blk, 0, stream>>>(e_bf16, wt3, c3b, 200, feats, 600);

    fc_head<<<dim3(NB), blk, 0, stream>>>(feats, f1w, f1b, f2w, f2b, f3w, f3b, out);
}

// Round 5
// 1241.896 us; speedup vs baseline: 6.7460x; 1.3681x over previous
//
#include <hip/hip_runtime.h>
#include <math.h>

namespace {

constexpr int NB    = 128;
constexpr int NPER  = 205;
constexpr int H     = 200;
constexpr int EMBD  = 768;
constexpr int SEQ   = 512;
constexpr int NLAY  = 6;
constexpr int NNODE = NB * NPER;   // 26240
constexpr int NEDGE = 209920;

typedef __bf16 bf16;
typedef _Float16 f16;
typedef __attribute__((ext_vector_type(8))) __bf16 bf16x8;
typedef __attribute__((ext_vector_type(8))) _Float16 f16x8;
typedef __attribute__((ext_vector_type(4))) float f32x4;
typedef unsigned short ushort8 __attribute__((ext_vector_type(8)));
typedef float float4v __attribute__((ext_vector_type(4)));

__device__ __forceinline__ float sigm(float x) { return 1.0f / (1.0f + expf(-x)); }

__device__ __forceinline__ unsigned short f2bf(float x) {
    unsigned int u = __float_as_uint(x);
    unsigned int r = (u + 0x7fffu + ((u >> 16) & 1u)) >> 16;
    return (unsigned short)r;
}
__device__ __forceinline__ unsigned short f2h(float x) {
    union { f16 h; unsigned short u; } c;
    c.h = (f16)x;
    return c.u;
}
__device__ __forceinline__ float h2f(unsigned short u) {
    union { unsigned short u; f16 h; } c;
    c.u = u;
    return (float)c.h;
}

// ================= fp16 MFMA GEMM =================
// C[M][Nreal] (+bias) = A[M][K] @ B^T ; A fp16 [M][lda] (cols in [0,Kpad)),
// B fp16 [Npad][Kpad] row-major K-contiguous (row = output col).
template<bool BIAS, bool OUTF16>
__global__ __launch_bounds__(256)
void gemm_f16_mfma(const unsigned short* __restrict__ A, int lda,
                   const unsigned short* __restrict__ B,
                   const float* __restrict__ bias, int Nreal,
                   float* __restrict__ Cf, unsigned short* __restrict__ Ch,
                   int ldc, int Kpad)
{
    __shared__ unsigned short As[128 * 64];
    __shared__ unsigned short Bs[64 * 64];

    const int p0 = blockIdx.x * 128;
    const int o0 = blockIdx.y * 64;
    const int tid = threadIdx.x, lane = tid & 63, wid = tid >> 6;
    const int wm = wid >> 1, wn = wid & 1;
    const int lrow = lane & 15, lk = lane >> 4;

    f32x4 acc[4][2];
    #pragma unroll
    for (int i = 0; i < 4; ++i)
        #pragma unroll
        for (int j = 0; j < 2; ++j) acc[i][j] = (f32x4){0.f, 0.f, 0.f, 0.f};

    for (int c0 = 0; c0 < Kpad; c0 += 64) {
        __syncthreads();
        for (int i = wid; i < 16; i += 4) {
            int u = i * 64 + lane;
            int row = u >> 3, slot = u & 7;
            int ss = slot ^ (row & 7);
            const unsigned short* sA = A + (size_t)(p0 + row) * lda + c0 + ss * 8;
            __builtin_amdgcn_global_load_lds(
                (const __attribute__((address_space(1))) void*)sA,
                (__attribute__((address_space(3))) void*)(As + i * 512), 16, 0, 0);
        }
        for (int i = wid; i < 8; i += 4) {
            int u = i * 64 + lane;
            int row = u >> 3, slot = u & 7;
            int ss = slot ^ (row & 7);
            const unsigned short* sB = B + (size_t)(o0 + row) * Kpad + c0 + ss * 8;
            __builtin_amdgcn_global_load_lds(
                (const __attribute__((address_space(1))) void*)sB,
                (__attribute__((address_space(3))) void*)(Bs + i * 512), 16, 0, 0);
        }
        __syncthreads();
        #pragma unroll
        for (int hf = 0; hf < 2; ++hf) {
            f16x8 vb[2];
            #pragma unroll
            for (int fn = 0; fn < 2; ++fn) {
                int r = wn * 32 + fn * 16 + lrow;
                int sl = (hf * 4 + lk) ^ (r & 7);
                vb[fn] = *reinterpret_cast<const f16x8*>(&Bs[r * 64 + sl * 8]);
            }
            #pragma unroll
            for (int fm = 0; fm < 4; ++fm) {
                int r = wm * 64 + fm * 16 + lrow;
                int sl = (hf * 4 + lk) ^ (r & 7);
                f16x8 va = *reinterpret_cast<const f16x8*>(&As[r * 64 + sl * 8]);
                #pragma unroll
                for (int fn = 0; fn < 2; ++fn)
                    acc[fm][fn] = __builtin_amdgcn_mfma_f32_16x16x32_f16(va, vb[fn], acc[fm][fn], 0, 0, 0);
            }
        }
    }
    #pragma unroll
    for (int fn = 0; fn < 2; ++fn) {
        int o = o0 + wn * 32 + fn * 16 + lrow;
        if (o >= Nreal) continue;
        float bv = BIAS ? bias[o] : 0.0f;
        #pragma unroll
        for (int fm = 0; fm < 4; ++fm) {
            #pragma unroll
            for (int i = 0; i < 4; ++i) {
                int p = p0 + wm * 64 + fm * 16 + lk * 4 + i;
                float v = acc[fm][fn][i] + bv;
                if (OUTF16) Ch[(size_t)p * ldc + o] = f2h(v);
                else        Cf[(size_t)p * ldc + o] = v;
            }
        }
    }
}

// ================= CSR build =================
__global__ void hist_kernel(const int* __restrict__ dst, int* __restrict__ deg)
{
    int e = blockIdx.x * 256 + threadIdx.x;
    if (e < NEDGE) atomicAdd(&deg[dst[e]], 1);
}

__global__ void scan_kernel(const int* __restrict__ deg, int* __restrict__ off, int* __restrict__ cur)
{
    __shared__ int part[1024];
    const int tid = threadIdx.x;
    const int CH = (NNODE + 1023) / 1024;
    int base = tid * CH;
    int s = 0;
    for (int i = 0; i < CH; ++i) { int idx = base + i; s += (idx < NNODE ? deg[idx] : 0); }
    part[tid] = s;
    __syncthreads();
    for (int d = 1; d < 1024; d <<= 1) {
        int v = (tid >= d) ? part[tid - d] : 0;
        __syncthreads();
        part[tid] += v;
        __syncthreads();
    }
    int run = tid ? part[tid - 1] : 0;
    for (int i = 0; i < CH; ++i) {
        int idx = base + i;
        if (idx < NNODE) { off[idx] = run; cur[idx] = run; run += deg[idx]; }
    }
    if (tid == 1023) off[NNODE] = run;
}

__global__ void fill_kernel(const int* __restrict__ src, const int* __restrict__ dst,
                            int* __restrict__ cur, int* __restrict__ eidx)
{
    int e = blockIdx.x * 256 + threadIdx.x;
    if (e >= NEDGE) return;
    int d = dst[e];
    int pos = atomicAdd(&cur[d], 1);
    eidx[pos] = src[e];
}

// ================= per-layer kernels =================
// gather: agg[n] = sum of m[src] over in-edges; write fp16 into acat cols [0,256)
__global__ void gather_h(const unsigned short* __restrict__ m,
                         const int* __restrict__ off, const int* __restrict__ eidx,
                         unsigned short* __restrict__ acat)
{
    int t = blockIdx.x * 256 + threadIdx.x;
    if (t >= NNODE * 32) return;
    int c8 = t & 31, n = t >> 5;
    float s[8] = {0.f, 0.f, 0.f, 0.f, 0.f, 0.f, 0.f, 0.f};
    if (c8 < 25) {
        const size_t cb = (size_t)c8 * 8;
        int beg = off[n], end = off[n + 1];
        for (int i = beg; i < end; ++i) {
            int sn = eidx[i];
            ushort8 mh = *(const ushort8*)(m + (size_t)sn * 208 + cb);
            #pragma unroll
            for (int j = 0; j < 8; ++j) s[j] += h2f(mh[j]);
        }
    }
    ushort8 o;
    #pragma unroll
    for (int j = 0; j < 8; ++j) o[j] = f2h(s[j]);
    *(ushort8*)(acat + (size_t)n * 512 + c8 * 8) = o;
}

// GRU update: h stored fp16 in acat cols [256,512)
__global__ void gru_kernel(const float* __restrict__ Srz, const float* __restrict__ inn,
                           const float* __restrict__ hn, unsigned short* __restrict__ acat)
{
    int gid = blockIdx.x * 256 + threadIdx.x;
    if (gid >= NNODE * H) return;
    int n = gid / H, c = gid % H;
    float r = sigm(Srz[(size_t)n * 400 + c]);
    float z = sigm(Srz[(size_t)n * 400 + 200 + c]);
    float nn = tanhf(inn[(size_t)n * 200 + c] + r * hn[(size_t)n * 200 + c]);
    size_t hidx = (size_t)n * 512 + 256 + c;
    float h_old = h2f(acat[hidx]);
    float hnew = (1.0f - z) * nn + z * h_old;
    acat[hidx] = f2h(hnew);
}

// initial h = x (fp16) into acat cols [256,512); zero pad cols
__global__ void h0_kernel(const float* __restrict__ x, unsigned short* __restrict__ acat)
{
    int t = blockIdx.x * 256 + threadIdx.x;
    if (t >= NNODE * 32) return;
    int c8 = t & 31, n = t >> 5;
    ushort8 o = {0,0,0,0,0,0,0,0};
    if (c8 < 25) {
        const float* src = x + (size_t)n * H + c8 * 8;
        float4v v0 = *(const float4v*)src;
        float4v v1 = *(const float4v*)(src + 4);
        o[0] = f2h(v0[0]); o[1] = f2h(v0[1]); o[2] = f2h(v0[2]); o[3] = f2h(v0[3]);
        o[4] = f2h(v1[0]); o[5] = f2h(v1[1]); o[6] = f2h(v1[2]); o[7] = f2h(v1[3]);
    }
    *(ushort8*)(acat + (size_t)n * 512 + 256 + c8 * 8) = o;
}

// ================= weight prep (fp16) =================
// ggc_w[l][in][out] -> wg[l][out(256)][in(256)]
__global__ void ggcw_h(const float* __restrict__ w, unsigned short* __restrict__ wg)
{
    int t = blockIdx.x * 256 + threadIdx.x;
    if (t >= NLAY * 256 * 32) return;
    int c8 = t & 31;
    int rest = t >> 5;
    int n = rest & 255;
    int l = rest >> 8;
    ushort8 o = {0,0,0,0,0,0,0,0};
    #pragma unroll
    for (int j = 0; j < 8; ++j) {
        int k = c8 * 8 + j;
        float v = 0.0f;
        if (n < H && k < H) v = w[(size_t)l * H * H + (size_t)k * H + n];
        o[j] = f2h(v);
    }
    *(ushort8*)(wg + (size_t)l * 65536 + (size_t)n * 256 + c8 * 8) = o;
}

// wcat[448][512]: row r<400: cols 0..199 = wih[r], cols 256..455 = whh[r]
__global__ void wcat_h(const float* __restrict__ wih, const float* __restrict__ whh,
                       unsigned short* __restrict__ wc)
{
    int t = blockIdx.x * 256 + threadIdx.x;
    if (t >= 448 * 64) return;
    int k8 = t & 63, r = t >> 6;
    ushort8 o = {0,0,0,0,0,0,0,0};
    #pragma unroll
    for (int j = 0; j < 8; ++j) {
        int kk = k8 * 8 + j;
        float v = 0.0f;
        if (r < 400) {
            if (kk < H) v = wih[(size_t)r * H + kk];
            else if (kk >= 256 && kk < 256 + H) v = whh[(size_t)r * H + (kk - 256)];
        }
        o[j] = f2h(v);
    }
    *(ushort8*)(wc + (size_t)r * 512 + k8 * 8) = o;
}

// src rows srow0.. -> [256][256] fp16
__global__ void wsplit_h(const float* __restrict__ src, int srow0, unsigned short* __restrict__ wo)
{
    int t = blockIdx.x * 256 + threadIdx.x;
    if (t >= 256 * 32) return;
    int k8 = t & 31, r = t >> 5;
    ushort8 o = {0,0,0,0,0,0,0,0};
    #pragma unroll
    for (int j = 0; j < 8; ++j) {
        int k = k8 * 8 + j;
        float v = 0.0f;
        if (r < H && k < H) v = src[(size_t)(srow0 + r) * H + k];
        o[j] = f2h(v);
    }
    *(ushort8*)(wo + (size_t)r * 256 + k8 * 8) = o;
}

__global__ void bias_prep(const float* __restrict__ bih, const float* __restrict__ bhh,
                          float* __restrict__ b_rz, float* __restrict__ b_inn, float* __restrict__ b_hn)
{
    int t = threadIdx.x;
    if (t < 400) b_rz[t] = bih[t] + bhh[t];
    if (t < 200) { b_inn[t] = bih[400 + t]; b_hn[t] = bhh[400 + t]; }
}

// ================= conv phase (verified rounds 3/4) =================
__global__ void embed_bf16_kernel(const int* __restrict__ ids, const float* __restrict__ table,
                                  unsigned short* __restrict__ e)
{
    int t = blockIdx.x * 256 + threadIdx.x;
    const int total = NB * SEQ * (EMBD / 8);
    if (t >= total) return;
    int j = t % (EMBD / 8), row = t / (EMBD / 8);
    int id = ids[row];
    const float* src = table + (size_t)id * EMBD + j * 8;
    float4v v0 = *(const float4v*)src;
    float4v v1 = *(const float4v*)(src + 4);
    ushort8 o;
    o[0] = f2bf(v0[0]); o[1] = f2bf(v0[1]); o[2] = f2bf(v0[2]); o[3] = f2bf(v0[3]);
    o[4] = f2bf(v1[0]); o[5] = f2bf(v1[1]); o[6] = f2bf(v1[2]); o[7] = f2bf(v1[3]);
    *(ushort8*)(e + (size_t)row * EMBD + j * 8) = o;
}

// e0[b][208][256] (bf16) from acat fp16 h-part; rows 1..205 = nodes, pad rows zero
__global__ void h_pad_from_acat(const unsigned short* __restrict__ acat,
                                unsigned short* __restrict__ e0)
{
    int t = blockIdx.x * 256 + threadIdx.x;
    const int total = NB * 208 * 32;
    if (t >= total) return;
    int c8 = t % 32, rest = t / 32;
    int r = rest % 208, b = rest / 208;
    ushort8 o = {0,0,0,0,0,0,0,0};
    if (r >= 1 && r <= 205) {
        int node = b * NPER + (r - 1);
        ushort8 hh = *(const ushort8*)(acat + (size_t)node * 512 + 256 + c8 * 8);
        #pragma unroll
        for (int j = 0; j < 8; ++j) o[j] = f2bf(h2f(hh[j]));
    }
    *(ushort8*)(e0 + ((size_t)(b * 208 + r)) * 256 + c8 * 8) = o;
}

__global__ void wconv_bf16_kernel(const float* __restrict__ w, unsigned short* __restrict__ wt,
                                  int K, int CINP, int CINR, int COUT)
{
    long long t = (long long)blockIdx.x * 256 + threadIdx.x;
    long long total = (long long)K * 256 * CINP;
    if (t >= total) return;
    int cin = (int)(t % CINP);
    long long rest = t / CINP;
    int o = (int)(rest % 256), k = (int)(rest / 256);
    float v = 0.0f;
    if (o < COUT && cin < CINR) v = w[((size_t)o * CINR + cin) * K + k];
    wt[t] = f2bf(v);
}

template<int K, int CINP, int LIN, int LOUT>
__global__ __launch_bounds__(256)
void conv_mfma(const unsigned short* __restrict__ E, const unsigned short* __restrict__ WT,
               const float* __restrict__ bias, int COUT,
               float* __restrict__ feats, int foff)
{
    constexpr int BM = 128;
    constexpr int WROWS = 136;
    constexpr int AINSTR = (WROWS * 64 * 2) / 1024;
    constexpr int BINSTR = (K * 64 * 64 * 2) / 1024;
    __shared__ unsigned short As[WROWS * 64];
    __shared__ unsigned short Bs[K * 64 * 64];

    const int p0 = blockIdx.x * BM;
    const int o0 = blockIdx.y * 64;
    const int b  = blockIdx.z;
    const int tid = threadIdx.x, lane = tid & 63, wid = tid >> 6;
    const int wm = wid >> 1, wn = wid & 1;
    const int lrow = lane & 15, lk = lane >> 4;

    const unsigned short* Eb = E + (size_t)b * LIN * CINP;

    f32x4 acc[4][2];
    #pragma unroll
    for (int i = 0; i < 4; ++i)
        #pragma unroll
        for (int j = 0; j < 2; ++j) acc[i][j] = (f32x4){0.f, 0.f, 0.f, 0.f};

    for (int c0 = 0; c0 < CINP; c0 += 64) {
        __syncthreads();
        for (int i = wid; i < AINSTR; i += 4) {
            int u = i * 64 + lane;
            int row = u >> 3, slot = u & 7;
            int srow = p0 + row; if (srow > LIN - 1) srow = LIN - 1;
            int sslot = slot ^ (row & 7);
            const unsigned short* src = Eb + (size_t)srow * CINP + c0 + sslot * 8;
            __builtin_amdgcn_global_load_lds(
                (const __attribute__((address_space(1))) void*)src,
                (__attribute__((address_space(3))) void*)(As + i * 512), 16, 0, 0);
        }
        for (int i = wid; i < BINSTR; i += 4) {
            int u = i * 64 + lane;
            int row = u >> 3, slot = u & 7;
            int k = row >> 6, r = row & 63;
            int sslot = slot ^ (r & 7);
            const unsigned short* src = WT + ((size_t)k * 256 + o0 + r) * CINP + c0 + sslot * 8;
            __builtin_amdgcn_global_load_lds(
                (const __attribute__((address_space(1))) void*)src,
                (__attribute__((address_space(3))) void*)(Bs + i * 512), 16, 0, 0);
        }
        __syncthreads();
        #pragma unroll
        for (int hf = 0; hf < 2; ++hf) {
            bf16x8 bf[K][2];
            #pragma unroll
            for (int k = 0; k < K; ++k)
                #pragma unroll
                for (int fn = 0; fn < 2; ++fn) {
                    int r = wn * 32 + fn * 16 + lrow;
                    int slot = (hf * 4 + lk) ^ (r & 7);
                    bf[k][fn] = *reinterpret_cast<const bf16x8*>(&Bs[(k * 64 + r) * 64 + slot * 8]);
                }
            #pragma unroll
            for (int k = 0; k < K; ++k) {
                bf16x8 av[4];
                #pragma unroll
                for (int fm = 0; fm < 4; ++fm) {
                    int r = wm * 64 + fm * 16 + lrow + k;
                    int slot = (hf * 4 + lk) ^ (r & 7);
                    av[fm] = *reinterpret_cast<const bf16x8*>(&As[r * 64 + slot * 8]);
                }
                #pragma unroll
                for (int fm = 0; fm < 4; ++fm)
                    #pragma unroll
                    for (int fn = 0; fn < 2; ++fn)
                        acc[fm][fn] = __builtin_amdgcn_mfma_f32_16x16x32_bf16(
                            av[fm], bf[k][fn], acc[fm][fn], 0, 0, 0);
            }
        }
    }
    #pragma unroll
    for (int fn = 0; fn < 2; ++fn) {
        int o = o0 + wn * 32 + fn * 16 + lrow;
        float mx = 0.0f;
        if (o < COUT) {
            float bv = bias[o];
            #pragma unroll
            for (int fm = 0; fm < 4; ++fm)
                #pragma unroll
                for (int i = 0; i < 4; ++i) {
                    int p = p0 + wm * 64 + fm * 16 + lk * 4 + i;
                    if (p < LOUT) mx = fmaxf(mx, acc[fm][fn][i] + bv);
                }
        }
        mx = fmaxf(mx, __shfl_xor(mx, 16));
        mx = fmaxf(mx, __shfl_xor(mx, 32));
        if (lane < 16 && o < COUT)
            atomicMax((int*)&feats[(size_t)b * 800 + foff + o], __float_as_int(mx));
    }
}

__global__ __launch_bounds__(256)
void fc_head(const float* __restrict__ feats,
             const float* __restrict__ w1, const float* __restrict__ b1,
             const float* __restrict__ w2, const float* __restrict__ b2,
             const float* __restrict__ w3, const float* __restrict__ b3,
             float* __restrict__ out)
{
    __shared__ float f[800];
    __shared__ float h1[256];
    __shared__ float h2[128];
    const int b = blockIdx.x, tid = threadIdx.x;
    for (int i = tid; i < 800; i += 256) f[i] = feats[(size_t)b * 800 + i];
    __syncthreads();
    {
        float acc = b1[tid];
        const float* wr = w1 + (size_t)tid * 800;
        for (int k = 0; k < 800; ++k) acc = fmaf(f[k], wr[k], acc);
        h1[tid] = fmaxf(acc, 0.0f);
    }
    __syncthreads();
    if (tid < 128) {
        float acc = b2[tid];
        const float* wr = w2 + (size_t)tid * 256;
        for (int k = 0; k < 256; ++k) acc = fmaf(h1[k], wr[k], acc);
        h2[tid] = fmaxf(acc, 0.0f);
    }
    __syncthreads();
    if (tid < 2) {
        float acc = b3[tid];
        const float* wr = w3 + (size_t)tid * 128;
        for (int k = 0; k < 128; ++k) acc = fmaf(h2[k], wr[k], acc);
        out[(size_t)b * 2 + tid] = acc;
    }
}

} // namespace

extern "C" void kernel_launch(void* const* d_in, const int* in_sizes, int n_in,
                              void* d_out, int out_size, void* d_ws, size_t ws_size,
                              hipStream_t stream)
{
    const float* x         = (const float*)d_in[0];
    const int*   edge      = (const int*)d_in[1];
    const int*   input_ids = (const int*)d_in[2];
    const float* table     = (const float*)d_in[3];
    const float* ggc_w     = (const float*)d_in[4];
    const float* wih       = (const float*)d_in[5];
    const float* whh       = (const float*)d_in[6];
    const float* bih       = (const float*)d_in[7];
    const float* bhh       = (const float*)d_in[8];
    const float* c0w = (const float*)d_in[9];  const float* c0b = (const float*)d_in[10];
    const float* c1w = (const float*)d_in[11]; const float* c1b = (const float*)d_in[12];
    const float* c2w = (const float*)d_in[13]; const float* c2b = (const float*)d_in[14];
    const float* c3w = (const float*)d_in[15]; const float* c3b = (const float*)d_in[16];
    const float* f1w = (const float*)d_in[17]; const float* f1b = (const float*)d_in[18];
    const float* f2w = (const float*)d_in[19]; const float* f2b = (const float*)d_in[20];
    const float* f3w = (const float*)d_in[21]; const float* f3b = (const float*)d_in[22];
    float* out = (float*)d_out;

    // ---- workspace layout (float-slot offsets) ----
    float* ws = (float*)d_ws;
    unsigned short* acat = (unsigned short*)(ws + 0);         // 26240*512 ush (agg|h fp16)
    float* Srz   = ws + 6717440;                              // 26240*400
    float* inn   = ws + 17213440;                             // 26240*200
    float* hn    = ws + 22461440;                             // 26240*200
    unsigned short* m16 = (unsigned short*)(ws + 27709440);   // 26240*208 ush
    unsigned short* wg  = (unsigned short*)(ws + 30438400);   // 6*256*256 ush
    unsigned short* wc  = (unsigned short*)(ws + 30635008);   // 448*512 ush
    unsigned short* win = (unsigned short*)(ws + 30749696);   // 256*256 ush
    unsigned short* whn = (unsigned short*)(ws + 30782464);   // 256*256 ush
    float* b_rz  = ws + 30815232;                             // 400
    float* b_inn = ws + 30815632;                             // 200
    float* b_hn  = ws + 30815832;                             // 200
    int* deg  = (int*)(ws + 30816032);                        // 26240
    int* off  = (int*)(ws + 30842272);                        // 26241
    int* cur  = (int*)(ws + 30868513);                        // 26241
    int* eidx = (int*)(ws + 30894754);                        // 209920
    float* feats = ws + 31300000;                             // 128*800
    // conv-phase aliases (GGC buffers dead by then):
    unsigned short* e_bf16 = (unsigned short*)(ws + 0);        // 128*512*768 ush = 25,165,824 f
    unsigned short* e0     = (unsigned short*)(ws + 25165824); // 128*208*256 ush =  3,407,872 f
    unsigned short* wt0    = (unsigned short*)(ws + 28600000); // 2,555,904 ush total
    unsigned short* wt1    = wt0 + (size_t)3 * 256 * 256;
    unsigned short* wt2    = wt1 + (size_t)3 * 256 * EMBD;
    unsigned short* wt3    = wt2 + (size_t)4 * 256 * EMBD;

    const int* srcp = edge;
    const int* dstp = edge + NEDGE;

    dim3 blk(256);

    // ---- one-time prep ----
    bias_prep<<<dim3(1), dim3(512), 0, stream>>>(bih, bhh, b_rz, b_inn, b_hn);
    hipMemsetAsync(deg, 0, sizeof(int) * NNODE, stream);
    hist_kernel<<<dim3((NEDGE + 255) / 256), blk, 0, stream>>>(dstp, deg);
    scan_kernel<<<dim3(1), dim3(1024), 0, stream>>>(deg, off, cur);
    fill_kernel<<<dim3((NEDGE + 255) / 256), blk, 0, stream>>>(srcp, dstp, cur, eidx);
    h0_kernel<<<dim3((NNODE * 32 + 255) / 256), blk, 0, stream>>>(x, acat);
    ggcw_h<<<dim3((NLAY * 256 * 32 + 255) / 256), blk, 0, stream>>>(ggc_w, wg);
    wcat_h<<<dim3((448 * 64 + 255) / 256), blk, 0, stream>>>(wih, whh, wc);
    wsplit_h<<<dim3((256 * 32 + 255) / 256), blk, 0, stream>>>(wih, 400, win);
    wsplit_h<<<dim3((256 * 32 + 255) / 256), blk, 0, stream>>>(whh, 400, whn);

    // ---- GGC layers (fp16 MFMA) ----
    const int GX = NNODE / 128;   // 205
    for (int l = 0; l < NLAY; ++l) {
        // m = h @ W_l  (fp16 out)
        gemm_f16_mfma<false, true><<<dim3(GX, 4), blk, 0, stream>>>(
            acat + 256, 512, wg + (size_t)l * 65536,
            nullptr, 200, nullptr, m16, 208, 256);
        // agg = gather(m)
        gather_h<<<dim3((NNODE * 32 + 255) / 256), blk, 0, stream>>>(m16, off, eidx, acat);
        // S_rz = [agg|h] @ wcat^T + (bih+bhh)[0:400]
        gemm_f16_mfma<true, false><<<dim3(GX, 7), blk, 0, stream>>>(
            acat, 512, wc, b_rz, 400, Srz, nullptr, 400, 512);
        // inn = agg @ wih_n^T + bih_n
        gemm_f16_mfma<true, false><<<dim3(GX, 4), blk, 0, stream>>>(
            acat, 512, win, b_inn, 200, inn, nullptr, 200, 256);
        // hn = h @ whh_n^T + bhh_n
        gemm_f16_mfma<true, false><<<dim3(GX, 4), blk, 0, stream>>>(
            acat + 256, 512, whn, b_hn, 200, hn, nullptr, 200, 256);
        // GRU update
        gru_kernel<<<dim3((NNODE * H + 255) / 256), blk, 0, stream>>>(Srz, inn, hn, acat);
    }

    // ---- conv phase ----
    h_pad_from_acat<<<dim3((NB * 208 * 32 + 255) / 256), blk, 0, stream>>>(acat, e0);
    embed_bf16_kernel<<<dim3(NB * SEQ * (EMBD / 8) / 256), blk, 0, stream>>>(input_ids, table, e_bf16);
    wconv_bf16_kernel<<<dim3((3 * 256 * 256 + 255) / 256), blk, 0, stream>>>(c0w, wt0, 3, 256, 200, 200);
    wconv_bf16_kernel<<<dim3((3 * 256 * EMBD + 255) / 256), blk, 0, stream>>>(c1w, wt1, 3, EMBD, EMBD, 200);
    wconv_bf16_kernel<<<dim3((4 * 256 * EMBD + 255) / 256), blk, 0, stream>>>(c2w, wt2, 4, EMBD, EMBD, 200);
    wconv_bf16_kernel<<<dim3((5 * 256 * EMBD + 255) / 256), blk, 0, stream>>>(c3w, wt3, 5, EMBD, EMBD, 200);

    hipMemsetAsync(feats, 0, sizeof(float) * NB * 800, stream);
    conv_mfma<3, 256, 208, 205><<<dim3(2, 4, NB), blk, 0, stream>>>(e0, wt0, c0b, 200, feats, 0);
    conv_mfma<3, EMBD, SEQ, 510><<<dim3(4, 4, NB), blk, 0, stream>>>(e_bf16, wt1, c1b, 200, feats, 200);
    conv_mfma<4, EMBD, SEQ, 509><<<dim3(4, 4, NB), blk, 0, stream>>>(e_bf16, wt2, c2b, 200, feats, 400);
    conv_mfma<5, EMBD, SEQ, 508><<<dim3(4, 4, NB), blk, 0, stream>>>(e_bf16, wt3, c3b, 200, feats, 600);

    fc_head<<<dim3(NB), blk, 0, stream>>>(feats, f1w, f1b, f2w, f2b, f3w, f3b, out);
}